// Round 13
// baseline (143.977 us; speedup 1.0000x reference)
//
#include <hip/hip_runtime.h>
#include <stdint.h>

// NCA step v11: flat 64x4 block tiles for contiguous DRAM segments.
//  - Block stages a 6x66 halo (bf16, ch-interleaved pitch 24) cooperatively:
//    PLANE reads land in 1056-B contiguous runs, ~8 dwordx4 in flight/lane.
//    One __syncthreads (halo), then waves are autonomous (each owns 1 row).
//  - GEMM1 operand-swapped (A=W1 frags, B=perc regs; same packed bytes as
//    before since A/B fragment lane layouts coincide) -> H stored with
//    ds_write_b64 (32 ops) instead of 128 b16; bias via f32x4.
//  - PLANE fp32 intermediates (v10): 5 planes of [b][px][4ch]; steps 0/3
//    convert from/to NCHW. d_ws/d_out ping-pong.
// B=8, C=20, H=W=256, HID=128, K_in=60 (pad 64), steps=4.

#define Bsz 8
#define Cn  20
#define Hn  256
#define Wn  256
#define HW  (Hn*Wn)

typedef float  f32x4  __attribute__((ext_vector_type(4)));
typedef __bf16 bf16x8 __attribute__((ext_vector_type(8)));
typedef __bf16 bf16x4 __attribute__((ext_vector_type(4)));
typedef short  s16x8  __attribute__((ext_vector_type(8)));

// Prepacked MFMA weight fragments + conv filters (rewritten each launch).
__device__ __bf16 g_W1p[128 * 64];        // GEMM1 A-frags (same bytes as v10 B-frags)
__device__ __bf16 g_W2p[2 * 4 * 64 * 8];  // GEMM2 A-frags
__device__ float  g_wf1[Cn * 9];
__device__ float  g_wf2[Cn * 9];

// Threefry-2x32, 20 rounds (verified r1: matches jax threefry_partitionable).
__device__ __host__ __forceinline__ void tf2x32(uint32_t k0, uint32_t k1,
                                                uint32_t x0, uint32_t x1,
                                                uint32_t& o0, uint32_t& o1) {
  uint32_t ks2 = k0 ^ k1 ^ 0x1BD11BDAu;
  x0 += k0; x1 += k1;
#define TFR(r) { x0 += x1; x1 = (x1 << (r)) | (x1 >> (32 - (r))); x1 ^= x0; }
  TFR(13) TFR(15) TFR(26) TFR(6)
  x0 += k1;  x1 += ks2 + 1u;
  TFR(17) TFR(29) TFR(16) TFR(24)
  x0 += ks2; x1 += k0 + 2u;
  TFR(13) TFR(15) TFR(26) TFR(6)
  x0 += k0;  x1 += k1 + 3u;
  TFR(17) TFR(29) TFR(16) TFR(24)
  x0 += k1;  x1 += ks2 + 4u;
  TFR(13) TFR(15) TFR(26) TFR(6)
  x0 += ks2; x1 += k0 + 5u;
#undef TFR
  o0 = x0; o1 = x1;
}

__device__ __forceinline__ f32x4 mfma16(bf16x8 a, bf16x8 b, f32x4 c) {
  return __builtin_amdgcn_mfma_f32_16x16x32_bf16(
      __builtin_bit_cast(s16x8, a), __builtin_bit_cast(s16x8, b), c, 0, 0, 0);
}

// W1p: i = (((q*2+jt)*2+kb)*64 + l)*8 + e:
//   j = q*32+jt*16+(l&15), k = kb*32+(l>>4)*8+e -> W1[j][k] (k<60 else 0).
//   (A-frag and B-frag lane layouts coincide for 16x16x32.)
// W2p: i = ((mt*4+q)*512 + l*8 + e): ch = mt*16+(l&15), j = q*32+(l>>4)*8+e
//   -> W2[ch][j] for 3<=ch<20 else 0.
__global__ void pack_weights(const float* __restrict__ W1, const float* __restrict__ W2,
                             const float* __restrict__ wf1, const float* __restrict__ wf2) {
  int t = blockIdx.x * 256 + threadIdx.x;
  for (int i = t; i < 128 * 64; i += gridDim.x * 256) {
    int e = i & 7, l = (i >> 3) & 63, kb = (i >> 9) & 1, jt = (i >> 10) & 1, q = i >> 11;
    int j = q * 32 + jt * 16 + (l & 15);
    int k = kb * 32 + (l >> 4) * 8 + e;
    g_W1p[i] = (k < 60) ? (__bf16)W1[j * 60 + k] : (__bf16)0.f;
  }
  for (int i = t; i < 2 * 4 * 512; i += gridDim.x * 256) {
    int e = i & 7, l = (i >> 3) & 63, q = (i >> 9) & 3, mt = i >> 11;
    int ch = mt * 16 + (l & 15);
    int j  = q * 32 + (l >> 4) * 8 + e;
    g_W2p[i] = (ch >= 3 && ch < Cn) ? (__bf16)W2[ch * 128 + j] : (__bf16)0.f;
  }
  for (int i = t; i < Cn * 9; i += gridDim.x * 256) {
    g_wf1[i] = wf1[i];
    g_wf2[i] = wf2[i];
  }
}

// SIN/SOUT: 0 = NCHW fp32 (harness x / final out), 1 = PLANE fp32.
template <int SIN, int SOUT>
__global__ __launch_bounds__(256, 4) void nca_step(
    const float* __restrict__ src, float* __restrict__ dst,
    const float* __restrict__ b1, uint32_t ka, uint32_t kb_key) {

  // halo: block-shared [6 rows][66 px][24 ch] bf16 = 19008 B.
  // r1  : per-wave [64 rows][40 cols] bf16 slices (perc/H chunks, dx f32).
  __shared__ __align__(16) __bf16 halo[6 * 66 * 24];
  __shared__ __align__(16) __bf16 r1all[4 * 2560];

  const int tid = threadIdx.x;
  const int w = tid >> 6, l = tid & 63;
  __bf16* r1 = r1all + w * 2560;

  // XCD swizzle: round-robin dispatch -> XCD k handles batch image k.
  const int lin = (blockIdx.z * 64 + blockIdx.y) * 4 + blockIdx.x;
  const int swzb = (lin & 7) * 256 + (lin >> 3);
  const int b   = swzb >> 8;
  const int rem = swzb & 255;
  const int by0 = (rem >> 2) * 4;       // tile row base (4 rows per block)
  const int bx0 = (rem & 3) * 64;       // tile col base (64 px per row)

  // ---- Stage 6x66 halo (reflect), channel-interleaved bf16 pitch 24 ----
  for (int t = tid; t < 6 * 66; t += 256) {
    int ry = t / 66, cx = t - ry * 66;
    int gy = by0 - 1 + ry; gy = (gy < 0) ? -gy : ((gy >= Hn) ? 2 * Hn - 2 - gy : gy);
    int gx = bx0 - 1 + cx; gx = (gx < 0) ? -gx : ((gx >= Wn) ? 2 * Wn - 2 - gx : gx);
    const int idx = gy * Wn + gx;
    bf16x8 q0, q1; bf16x4 q2;
    if constexpr (SIN == 0) {
      const float* sp = src + (size_t)b * Cn * HW + idx;
#pragma unroll
      for (int c = 0; c < 8; ++c)  q0[c] = (__bf16)sp[(size_t)c * HW];
#pragma unroll
      for (int c = 0; c < 8; ++c)  q1[c] = (__bf16)sp[(size_t)(c + 8) * HW];
#pragma unroll
      for (int c = 0; c < 4; ++c)  q2[c] = (__bf16)sp[(size_t)(c + 16) * HW];
    } else {
      const f32x4* pb = (const f32x4*)src;
      f32x4 v0 = pb[(0 * Bsz + b) * HW + idx];
      f32x4 v1 = pb[(1 * Bsz + b) * HW + idx];
      f32x4 v2 = pb[(2 * Bsz + b) * HW + idx];
      f32x4 v3 = pb[(3 * Bsz + b) * HW + idx];
      f32x4 v4 = pb[(4 * Bsz + b) * HW + idx];
#pragma unroll
      for (int c = 0; c < 4; ++c) { q0[c] = (__bf16)v0[c]; q0[c + 4] = (__bf16)v1[c]; }
#pragma unroll
      for (int c = 0; c < 4; ++c) { q1[c] = (__bf16)v2[c]; q1[c + 4] = (__bf16)v3[c]; }
#pragma unroll
      for (int c = 0; c < 4; ++c)  q2[c] = (__bf16)v4[c];
    }
    __bf16* wp = halo + t * 24;
    *(bf16x8*)(wp)      = q0;
    *(bf16x8*)(wp + 8)  = q1;
    *(bf16x4*)(wp + 16) = q2;
  }

  // Fire mask in the load shadow: wave w owns image row gy=by0+w, lane l
  // owns pixel gx = bx0 + l.
  const int gy = by0 + w;
  uint32_t y0, y1;
  tf2x32(ka, kb_key, 0u, (uint32_t)((b * Hn + gy) * Wn + bx0 + l), y0, y1);
  const unsigned long long fmask = __ballot(((y0 ^ y1) & 0x80000000u) == 0u);

  __syncthreads();   // halo visible to all waves; the only barrier

  // ---- Depthwise conv (fp32 math, bf16 taps); lane l = pixel (gy, bx0+l) ----
  float a1[Cn], a2[Cn];
#pragma unroll
  for (int c = 0; c < Cn; ++c) { a1[c] = 0.f; a2[c] = 0.f; }
  bf16x8 id0, id1; bf16x4 id2;   // center tap = identity slots of perc

#pragma unroll
  for (int ky = 0; ky < 3; ++ky)
#pragma unroll
    for (int kx = 0; kx < 3; ++kx) {
      const __bf16* tp = halo + ((w + ky) * 66 + l + kx) * 24;
      bf16x8 t0 = *(const bf16x8*)(tp);
      bf16x8 t1 = *(const bf16x8*)(tp + 8);
      bf16x4 t2 = *(const bf16x4*)(tp + 16);
      if (ky == 1 && kx == 1) { id0 = t0; id1 = t1; id2 = t2; }
      const int tap = ky * 3 + kx;
#pragma unroll
      for (int c = 0; c < 8; ++c) {
        float v = (float)t0[c];
        a1[c] = fmaf(g_wf1[c * 9 + tap], v, a1[c]);
        a2[c] = fmaf(g_wf2[c * 9 + tap], v, a2[c]);
      }
#pragma unroll
      for (int c = 0; c < 8; ++c) {
        float v = (float)t1[c];
        a1[c + 8] = fmaf(g_wf1[(c + 8) * 9 + tap], v, a1[c + 8]);
        a2[c + 8] = fmaf(g_wf2[(c + 8) * 9 + tap], v, a2[c + 8]);
      }
#pragma unroll
      for (int c = 0; c < 4; ++c) {
        float v = (float)t2[c];
        a1[c + 16] = fmaf(g_wf1[(c + 16) * 9 + tap], v, a1[c + 16]);
        a2[c + 16] = fmaf(g_wf2[(c + 16) * 9 + tap], v, a2[c + 16]);
      }
    }

  // ---- Pack perc -> r1 (32-k chunks), load perc fragments (M=64 px) ----
  const int g4 = l >> 4, c16 = l & 15;

  bf16x8 af[4][2];
#pragma unroll
  for (int kb = 0; kb < 2; ++kb) {
#pragma unroll
    for (int g2 = 0; g2 < 4; ++g2) {
      bf16x8 pk;
#pragma unroll
      for (int e = 0; e < 8; ++e) {
        const int k = kb * 32 + g2 * 8 + e;
        __bf16 v;
        if      (k < 8)  v = id0[k];
        else if (k < 16) v = id1[k - 8];
        else if (k < 20) v = id2[k - 16];
        else if (k < 40) v = (__bf16)a1[k - 20];
        else if (k < 60) v = (__bf16)a2[k - 40];
        else             v = (__bf16)0.f;
        pk[e] = v;
      }
      *(bf16x8*)(r1 + l * 40 + g2 * 8) = pk;   // own row l (wave-private slice)
    }
    // same-wave LDS ops are in-order: all lanes' writes precede these reads
#pragma unroll
    for (int pxt = 0; pxt < 4; ++pxt)
      af[pxt][kb] = *(const bf16x8*)(r1 + (pxt * 16 + c16) * 40 + g4 * 8);
  }

  // ---- GEMM chunks: per 32 j's: GEMM1 (swapped) -> H chunk -> GEMM2 ----
  const f32x4 zero4 = {0.f, 0.f, 0.f, 0.f};
  f32x4 acc2[2][4];
#pragma unroll
  for (int mt = 0; mt < 2; ++mt)
#pragma unroll
    for (int nt = 0; nt < 4; ++nt) acc2[mt][nt] = zero4;

  const bf16x8* w1v = (const bf16x8*)g_W1p;
  const bf16x8* w2v = (const bf16x8*)g_W2p;

  for (int q = 0; q < 4; ++q) {
    // GEMM1 swapped: D[j-in-32][px] = Weff_q @ perc^T; lane: col=c16 -> px,
    // row=g4*4+r -> j. H store = one b64 per (jt,pxt).
#pragma unroll
    for (int jt = 0; jt < 2; ++jt) {
      bf16x8 aw0 = w1v[((q * 2 + jt) * 2 + 0) * 64 + l];
      bf16x8 aw1 = w1v[((q * 2 + jt) * 2 + 1) * 64 + l];
      const f32x4 bias = *(const f32x4*)(b1 + q * 32 + jt * 16 + g4 * 4);
#pragma unroll
      for (int pxt = 0; pxt < 4; ++pxt) {
        f32x4 a = mfma16(aw0, af[pxt][0], zero4);
        a = mfma16(aw1, af[pxt][1], a);
        bf16x4 hv;
#pragma unroll
        for (int r = 0; r < 4; ++r)
          hv[r] = (__bf16)fmaxf(a[r] + bias[r], 0.f);
        *(bf16x4*)(r1 + (pxt * 16 + c16) * 40 + jt * 16 + g4 * 4) = hv;
      }
    }
    // GEMM2: dx[ch][px] += W2_q @ H_q^T (H cols 0..31 time-multiplexed)
    bf16x8 wa0 = w2v[(0 * 4 + q) * 64 + l];
    bf16x8 wa1 = w2v[(1 * 4 + q) * 64 + l];
#pragma unroll
    for (int nt = 0; nt < 4; ++nt) {
      bf16x8 hb = *(const bf16x8*)(r1 + (nt * 16 + c16) * 40 + g4 * 8);
      acc2[0][nt] = mfma16(wa0, hb, acc2[0][nt]);
      acc2[1][nt] = mfma16(wa1, hb, acc2[1][nt]);
    }
  }

  // ---- Epilogue ----
  if constexpr (SOUT == 1) {
    // dx transpose via LDS (r1 slice free now): [64 px][20ch] f32 = 5120 B.
    float* ldsf = (float*)r1;
#pragma unroll
    for (int nt = 0; nt < 4; ++nt) {
      const int px = nt * 16 + c16;
      *(f32x4*)(ldsf + px * 20 + g4 * 4) = acc2[0][nt];
      if (g4 == 0) *(f32x4*)(ldsf + px * 20 + 16) = acc2[1][nt];
    }
    // Own pixel: 5 dense plane reads (x) + 5 dense stores (1 KB/wave each).
    const int idx = gy * Wn + bx0 + l;
    const float fire = ((fmask >> l) & 1ull) ? 1.f : 0.f;
    f32x4* db = (f32x4*)dst;
#pragma unroll
    for (int p = 0; p < 5; ++p) {
      f32x4 dxv = *(const f32x4*)(ldsf + l * 20 + p * 4);
      f32x4 xv;
      if constexpr (SIN == 0) {
        const float* sp = src + (size_t)b * Cn * HW + idx;
#pragma unroll
        for (int r = 0; r < 4; ++r) xv[r] = sp[(size_t)(p * 4 + r) * HW];
      } else {
        xv = ((const f32x4*)src)[(p * Bsz + b) * HW + idx];
      }
      f32x4 ov;
#pragma unroll
      for (int r = 0; r < 4; ++r) ov[r] = xv[r] + dxv[r] * fire;
      db[(p * Bsz + b) * HW + idx] = ov;
    }
  } else {
    // NCHW out (final step; SIN==1). D: px = nt*16+c16, ch = mt*16+g4*4+r.
    float* __restrict__ ob = dst + (size_t)b * Cn * HW;
#pragma unroll
    for (int nt = 0; nt < 4; ++nt) {
      const int pxl = nt * 16 + c16;
      const size_t pix = (size_t)gy * Wn + bx0 + pxl;
      const float fire = ((fmask >> pxl) & 1ull) ? 1.f : 0.f;
#pragma unroll
      for (int mt = 0; mt < 2; ++mt) {
        if (mt == 0 || g4 == 0) {
          f32x4 xv = ((const f32x4*)src)[((mt * 4 + g4) * Bsz + b) * HW + pix];
#pragma unroll
          for (int r = 0; r < 4; ++r) {
            const int ch = mt * 16 + g4 * 4 + r;
            ob[(size_t)ch * HW + pix] = xv[r] + acc2[mt][nt][r] * fire;
          }
        }
      }
    }
  }
}

extern "C" void kernel_launch(void* const* d_in, const int* in_sizes, int n_in,
                              void* d_out, int out_size, void* d_ws, size_t ws_size,
                              hipStream_t stream) {
  const float* x   = (const float*)d_in[0];
  const float* wf1 = (const float*)d_in[1];
  const float* wf2 = (const float*)d_in[2];
  const float* W1  = (const float*)d_in[3];
  const float* b1  = (const float*)d_in[4];
  const float* W2  = (const float*)d_in[5];

  float* out = (float*)d_out;
  float* ws0 = (float*)d_ws;   // 41.94 MB = exactly one plane set

  pack_weights<<<8, 256, 0, stream>>>(W1, W2, wf1, wf2);

  dim3 grid(4, 64, Bsz);   // 64-wide x 4-tall tiles
  dim3 blk(256);

  // s0: x(NCHW)->ws(PLANE); s1: ws->out(PLANE); s2: out->ws(PLANE);
  // s3: ws->out(NCHW). d_out doubles as plane scratch mid-sequence.
  uint32_t ka, kb;
  tf2x32(0u, 42u, 0u, 0u, ka, kb);
  nca_step<0, 1><<<grid, blk, 0, stream>>>(x,   ws0, b1, ka, kb);
  tf2x32(0u, 42u, 0u, 1u, ka, kb);
  nca_step<1, 1><<<grid, blk, 0, stream>>>(ws0, out, b1, ka, kb);
  tf2x32(0u, 42u, 0u, 2u, ka, kb);
  nca_step<1, 1><<<grid, blk, 0, stream>>>(out, ws0, b1, ka, kb);
  tf2x32(0u, 42u, 0u, 3u, ka, kb);
  nca_step<1, 0><<<grid, blk, 0, stream>>>(ws0, out, b1, ka, kb);
}

// Round 14
// 142.807 us; speedup vs baseline: 1.0082x; 1.0082x over previous
//
#include <hip/hip_runtime.h>
#include <stdint.h>

// NCA step v11: flat 64x4 block tiles for contiguous DRAM segments.
//  - Block stages a 6x66 halo (bf16, ch-interleaved pitch 24) cooperatively:
//    PLANE reads land in 1056-B contiguous runs, ~8 dwordx4 in flight/lane.
//    One __syncthreads (halo), then waves are autonomous (each owns 1 row).
//  - GEMM1 operand-swapped (A=W1 frags, B=perc regs; same packed bytes as
//    before since A/B fragment lane layouts coincide) -> H stored with
//    ds_write_b64 (32 ops) instead of 128 b16; bias via f32x4.
//  - PLANE fp32 intermediates (v10): 5 planes of [b][px][4ch]; steps 0/3
//    convert from/to NCHW. d_ws/d_out ping-pong.
// B=8, C=20, H=W=256, HID=128, K_in=60 (pad 64), steps=4.

#define Bsz 8
#define Cn  20
#define Hn  256
#define Wn  256
#define HW  (Hn*Wn)

typedef float  f32x4  __attribute__((ext_vector_type(4)));
typedef __bf16 bf16x8 __attribute__((ext_vector_type(8)));
typedef __bf16 bf16x4 __attribute__((ext_vector_type(4)));
typedef short  s16x8  __attribute__((ext_vector_type(8)));

// Prepacked MFMA weight fragments + conv filters (rewritten each launch).
__device__ __bf16 g_W1p[128 * 64];        // GEMM1 A-frags (same bytes as v10 B-frags)
__device__ __bf16 g_W2p[2 * 4 * 64 * 8];  // GEMM2 A-frags
__device__ float  g_wf1[Cn * 9];
__device__ float  g_wf2[Cn * 9];

// Threefry-2x32, 20 rounds (verified r1: matches jax threefry_partitionable).
__device__ __host__ __forceinline__ void tf2x32(uint32_t k0, uint32_t k1,
                                                uint32_t x0, uint32_t x1,
                                                uint32_t& o0, uint32_t& o1) {
  uint32_t ks2 = k0 ^ k1 ^ 0x1BD11BDAu;
  x0 += k0; x1 += k1;
#define TFR(r) { x0 += x1; x1 = (x1 << (r)) | (x1 >> (32 - (r))); x1 ^= x0; }
  TFR(13) TFR(15) TFR(26) TFR(6)
  x0 += k1;  x1 += ks2 + 1u;
  TFR(17) TFR(29) TFR(16) TFR(24)
  x0 += ks2; x1 += k0 + 2u;
  TFR(13) TFR(15) TFR(26) TFR(6)
  x0 += k0;  x1 += k1 + 3u;
  TFR(17) TFR(29) TFR(16) TFR(24)
  x0 += k1;  x1 += ks2 + 4u;
  TFR(13) TFR(15) TFR(26) TFR(6)
  x0 += ks2; x1 += k0 + 5u;
#undef TFR
  o0 = x0; o1 = x1;
}

__device__ __forceinline__ f32x4 mfma16(bf16x8 a, bf16x8 b, f32x4 c) {
  return __builtin_amdgcn_mfma_f32_16x16x32_bf16(
      __builtin_bit_cast(s16x8, a), __builtin_bit_cast(s16x8, b), c, 0, 0, 0);
}

// W1p: i = (((q*2+jt)*2+kb)*64 + l)*8 + e:
//   j = q*32+jt*16+(l&15), k = kb*32+(l>>4)*8+e -> W1[j][k] (k<60 else 0).
//   (A-frag and B-frag lane layouts coincide for 16x16x32.)
// W2p: i = ((mt*4+q)*512 + l*8 + e): ch = mt*16+(l&15), j = q*32+(l>>4)*8+e
//   -> W2[ch][j] for 3<=ch<20 else 0.
__global__ void pack_weights(const float* __restrict__ W1, const float* __restrict__ W2,
                             const float* __restrict__ wf1, const float* __restrict__ wf2) {
  int t = blockIdx.x * 256 + threadIdx.x;
  for (int i = t; i < 128 * 64; i += gridDim.x * 256) {
    int e = i & 7, l = (i >> 3) & 63, kb = (i >> 9) & 1, jt = (i >> 10) & 1, q = i >> 11;
    int j = q * 32 + jt * 16 + (l & 15);
    int k = kb * 32 + (l >> 4) * 8 + e;
    g_W1p[i] = (k < 60) ? (__bf16)W1[j * 60 + k] : (__bf16)0.f;
  }
  for (int i = t; i < 2 * 4 * 512; i += gridDim.x * 256) {
    int e = i & 7, l = (i >> 3) & 63, q = (i >> 9) & 3, mt = i >> 11;
    int ch = mt * 16 + (l & 15);
    int j  = q * 32 + (l >> 4) * 8 + e;
    g_W2p[i] = (ch >= 3 && ch < Cn) ? (__bf16)W2[ch * 128 + j] : (__bf16)0.f;
  }
  for (int i = t; i < Cn * 9; i += gridDim.x * 256) {
    g_wf1[i] = wf1[i];
    g_wf2[i] = wf2[i];
  }
}

// SIN/SOUT: 0 = NCHW fp32 (harness x / final out), 1 = PLANE fp32.
template <int SIN, int SOUT>
__global__ __launch_bounds__(256, 4) void nca_step(
    const float* __restrict__ src, float* __restrict__ dst,
    const float* __restrict__ b1, uint32_t ka, uint32_t kb_key) {

  // halo: block-shared [6 rows][66 px][24 ch] bf16 = 19008 B.
  // r1  : per-wave [64 rows][40 cols] bf16 slices (perc/H chunks, dx f32).
  __shared__ __align__(16) __bf16 halo[6 * 66 * 24];
  __shared__ __align__(16) __bf16 r1all[4 * 2560];

  const int tid = threadIdx.x;
  const int w = tid >> 6, l = tid & 63;
  __bf16* r1 = r1all + w * 2560;

  // XCD swizzle: round-robin dispatch -> XCD k handles batch image k.
  const int lin = (blockIdx.z * 64 + blockIdx.y) * 4 + blockIdx.x;
  const int swzb = (lin & 7) * 256 + (lin >> 3);
  const int b   = swzb >> 8;
  const int rem = swzb & 255;
  const int by0 = (rem >> 2) * 4;       // tile row base (4 rows per block)
  const int bx0 = (rem & 3) * 64;       // tile col base (64 px per row)

  // ---- Stage 6x66 halo (reflect), channel-interleaved bf16 pitch 24 ----
  for (int t = tid; t < 6 * 66; t += 256) {
    int ry = t / 66, cx = t - ry * 66;
    int gy = by0 - 1 + ry; gy = (gy < 0) ? -gy : ((gy >= Hn) ? 2 * Hn - 2 - gy : gy);
    int gx = bx0 - 1 + cx; gx = (gx < 0) ? -gx : ((gx >= Wn) ? 2 * Wn - 2 - gx : gx);
    const int idx = gy * Wn + gx;
    bf16x8 q0, q1; bf16x4 q2;
    if constexpr (SIN == 0) {
      const float* sp = src + (size_t)b * Cn * HW + idx;
#pragma unroll
      for (int c = 0; c < 8; ++c)  q0[c] = (__bf16)sp[(size_t)c * HW];
#pragma unroll
      for (int c = 0; c < 8; ++c)  q1[c] = (__bf16)sp[(size_t)(c + 8) * HW];
#pragma unroll
      for (int c = 0; c < 4; ++c)  q2[c] = (__bf16)sp[(size_t)(c + 16) * HW];
    } else {
      const f32x4* pb = (const f32x4*)src;
      f32x4 v0 = pb[(0 * Bsz + b) * HW + idx];
      f32x4 v1 = pb[(1 * Bsz + b) * HW + idx];
      f32x4 v2 = pb[(2 * Bsz + b) * HW + idx];
      f32x4 v3 = pb[(3 * Bsz + b) * HW + idx];
      f32x4 v4 = pb[(4 * Bsz + b) * HW + idx];
#pragma unroll
      for (int c = 0; c < 4; ++c) { q0[c] = (__bf16)v0[c]; q0[c + 4] = (__bf16)v1[c]; }
#pragma unroll
      for (int c = 0; c < 4; ++c) { q1[c] = (__bf16)v2[c]; q1[c + 4] = (__bf16)v3[c]; }
#pragma unroll
      for (int c = 0; c < 4; ++c)  q2[c] = (__bf16)v4[c];
    }
    __bf16* wp = halo + t * 24;
    *(bf16x8*)(wp)      = q0;
    *(bf16x8*)(wp + 8)  = q1;
    *(bf16x4*)(wp + 16) = q2;
  }

  // Fire mask in the load shadow: wave w owns image row gy=by0+w, lane l
  // owns pixel gx = bx0 + l.
  const int gy = by0 + w;
  uint32_t y0, y1;
  tf2x32(ka, kb_key, 0u, (uint32_t)((b * Hn + gy) * Wn + bx0 + l), y0, y1);
  const unsigned long long fmask = __ballot(((y0 ^ y1) & 0x80000000u) == 0u);

  __syncthreads();   // halo visible to all waves; the only barrier

  // ---- Depthwise conv (fp32 math, bf16 taps); lane l = pixel (gy, bx0+l) ----
  float a1[Cn], a2[Cn];
#pragma unroll
  for (int c = 0; c < Cn; ++c) { a1[c] = 0.f; a2[c] = 0.f; }
  bf16x8 id0, id1; bf16x4 id2;   // center tap = identity slots of perc

#pragma unroll
  for (int ky = 0; ky < 3; ++ky)
#pragma unroll
    for (int kx = 0; kx < 3; ++kx) {
      const __bf16* tp = halo + ((w + ky) * 66 + l + kx) * 24;
      bf16x8 t0 = *(const bf16x8*)(tp);
      bf16x8 t1 = *(const bf16x8*)(tp + 8);
      bf16x4 t2 = *(const bf16x4*)(tp + 16);
      if (ky == 1 && kx == 1) { id0 = t0; id1 = t1; id2 = t2; }
      const int tap = ky * 3 + kx;
#pragma unroll
      for (int c = 0; c < 8; ++c) {
        float v = (float)t0[c];
        a1[c] = fmaf(g_wf1[c * 9 + tap], v, a1[c]);
        a2[c] = fmaf(g_wf2[c * 9 + tap], v, a2[c]);
      }
#pragma unroll
      for (int c = 0; c < 8; ++c) {
        float v = (float)t1[c];
        a1[c + 8] = fmaf(g_wf1[(c + 8) * 9 + tap], v, a1[c + 8]);
        a2[c + 8] = fmaf(g_wf2[(c + 8) * 9 + tap], v, a2[c + 8]);
      }
#pragma unroll
      for (int c = 0; c < 4; ++c) {
        float v = (float)t2[c];
        a1[c + 16] = fmaf(g_wf1[(c + 16) * 9 + tap], v, a1[c + 16]);
        a2[c + 16] = fmaf(g_wf2[(c + 16) * 9 + tap], v, a2[c + 16]);
      }
    }

  // ---- Pack perc -> r1 (32-k chunks), load perc fragments (M=64 px) ----
  const int g4 = l >> 4, c16 = l & 15;

  bf16x8 af[4][2];
#pragma unroll
  for (int kb = 0; kb < 2; ++kb) {
#pragma unroll
    for (int g2 = 0; g2 < 4; ++g2) {
      bf16x8 pk;
#pragma unroll
      for (int e = 0; e < 8; ++e) {
        const int k = kb * 32 + g2 * 8 + e;
        __bf16 v;
        if      (k < 8)  v = id0[k];
        else if (k < 16) v = id1[k - 8];
        else if (k < 20) v = id2[k - 16];
        else if (k < 40) v = (__bf16)a1[k - 20];
        else if (k < 60) v = (__bf16)a2[k - 40];
        else             v = (__bf16)0.f;
        pk[e] = v;
      }
      *(bf16x8*)(r1 + l * 40 + g2 * 8) = pk;   // own row l (wave-private slice)
    }
    // same-wave LDS ops are in-order: all lanes' writes precede these reads
#pragma unroll
    for (int pxt = 0; pxt < 4; ++pxt)
      af[pxt][kb] = *(const bf16x8*)(r1 + (pxt * 16 + c16) * 40 + g4 * 8);
  }

  // ---- GEMM chunks: per 32 j's: GEMM1 (swapped) -> H chunk -> GEMM2 ----
  const f32x4 zero4 = {0.f, 0.f, 0.f, 0.f};
  f32x4 acc2[2][4];
#pragma unroll
  for (int mt = 0; mt < 2; ++mt)
#pragma unroll
    for (int nt = 0; nt < 4; ++nt) acc2[mt][nt] = zero4;

  const bf16x8* w1v = (const bf16x8*)g_W1p;
  const bf16x8* w2v = (const bf16x8*)g_W2p;

  for (int q = 0; q < 4; ++q) {
    // GEMM1 swapped: D[j-in-32][px] = Weff_q @ perc^T; lane: col=c16 -> px,
    // row=g4*4+r -> j. H store = one b64 per (jt,pxt).
#pragma unroll
    for (int jt = 0; jt < 2; ++jt) {
      bf16x8 aw0 = w1v[((q * 2 + jt) * 2 + 0) * 64 + l];
      bf16x8 aw1 = w1v[((q * 2 + jt) * 2 + 1) * 64 + l];
      const f32x4 bias = *(const f32x4*)(b1 + q * 32 + jt * 16 + g4 * 4);
#pragma unroll
      for (int pxt = 0; pxt < 4; ++pxt) {
        f32x4 a = mfma16(aw0, af[pxt][0], zero4);
        a = mfma16(aw1, af[pxt][1], a);
        bf16x4 hv;
#pragma unroll
        for (int r = 0; r < 4; ++r)
          hv[r] = (__bf16)fmaxf(a[r] + bias[r], 0.f);
        *(bf16x4*)(r1 + (pxt * 16 + c16) * 40 + jt * 16 + g4 * 4) = hv;
      }
    }
    // GEMM2: dx[ch][px] += W2_q @ H_q^T (H cols 0..31 time-multiplexed)
    bf16x8 wa0 = w2v[(0 * 4 + q) * 64 + l];
    bf16x8 wa1 = w2v[(1 * 4 + q) * 64 + l];
#pragma unroll
    for (int nt = 0; nt < 4; ++nt) {
      bf16x8 hb = *(const bf16x8*)(r1 + (nt * 16 + c16) * 40 + g4 * 8);
      acc2[0][nt] = mfma16(wa0, hb, acc2[0][nt]);
      acc2[1][nt] = mfma16(wa1, hb, acc2[1][nt]);
    }
  }

  // ---- Epilogue ----
  if constexpr (SOUT == 1) {
    // dx transpose via LDS (r1 slice free now): [64 px][20ch] f32 = 5120 B.
    float* ldsf = (float*)r1;
#pragma unroll
    for (int nt = 0; nt < 4; ++nt) {
      const int px = nt * 16 + c16;
      *(f32x4*)(ldsf + px * 20 + g4 * 4) = acc2[0][nt];
      if (g4 == 0) *(f32x4*)(ldsf + px * 20 + 16) = acc2[1][nt];
    }
    // Own pixel: 5 dense plane reads (x) + 5 dense stores (1 KB/wave each).
    const int idx = gy * Wn + bx0 + l;
    const float fire = ((fmask >> l) & 1ull) ? 1.f : 0.f;
    f32x4* db = (f32x4*)dst;
#pragma unroll
    for (int p = 0; p < 5; ++p) {
      f32x4 dxv = *(const f32x4*)(ldsf + l * 20 + p * 4);
      f32x4 xv;
      if constexpr (SIN == 0) {
        const float* sp = src + (size_t)b * Cn * HW + idx;
#pragma unroll
        for (int r = 0; r < 4; ++r) xv[r] = sp[(size_t)(p * 4 + r) * HW];
      } else {
        xv = ((const f32x4*)src)[(p * Bsz + b) * HW + idx];
      }
      f32x4 ov;
#pragma unroll
      for (int r = 0; r < 4; ++r) ov[r] = xv[r] + dxv[r] * fire;
      db[(p * Bsz + b) * HW + idx] = ov;
    }
  } else {
    // NCHW out (final step; SIN==1). D: px = nt*16+c16, ch = mt*16+g4*4+r.
    float* __restrict__ ob = dst + (size_t)b * Cn * HW;
#pragma unroll
    for (int nt = 0; nt < 4; ++nt) {
      const int pxl = nt * 16 + c16;
      const size_t pix = (size_t)gy * Wn + bx0 + pxl;
      const float fire = ((fmask >> pxl) & 1ull) ? 1.f : 0.f;
#pragma unroll
      for (int mt = 0; mt < 2; ++mt) {
        if (mt == 0 || g4 == 0) {
          f32x4 xv = ((const f32x4*)src)[((mt * 4 + g4) * Bsz + b) * HW + pix];
#pragma unroll
          for (int r = 0; r < 4; ++r) {
            const int ch = mt * 16 + g4 * 4 + r;
            ob[(size_t)ch * HW + pix] = xv[r] + acc2[mt][nt][r] * fire;
          }
        }
      }
    }
  }
}

extern "C" void kernel_launch(void* const* d_in, const int* in_sizes, int n_in,
                              void* d_out, int out_size, void* d_ws, size_t ws_size,
                              hipStream_t stream) {
  const float* x   = (const float*)d_in[0];
  const float* wf1 = (const float*)d_in[1];
  const float* wf2 = (const float*)d_in[2];
  const float* W1  = (const float*)d_in[3];
  const float* b1  = (const float*)d_in[4];
  const float* W2  = (const float*)d_in[5];

  float* out = (float*)d_out;
  float* ws0 = (float*)d_ws;   // 41.94 MB = exactly one plane set

  pack_weights<<<8, 256, 0, stream>>>(W1, W2, wf1, wf2);

  dim3 grid(4, 64, Bsz);   // 64-wide x 4-tall tiles
  dim3 blk(256);

  // s0: x(NCHW)->ws(PLANE); s1: ws->out(PLANE); s2: out->ws(PLANE);
  // s3: ws->out(NCHW). d_out doubles as plane scratch mid-sequence.
  uint32_t ka, kb;
  tf2x32(0u, 42u, 0u, 0u, ka, kb);
  nca_step<0, 1><<<grid, blk, 0, stream>>>(x,   ws0, b1, ka, kb);
  tf2x32(0u, 42u, 0u, 1u, ka, kb);
  nca_step<1, 1><<<grid, blk, 0, stream>>>(ws0, out, b1, ka, kb);
  tf2x32(0u, 42u, 0u, 2u, ka, kb);
  nca_step<1, 1><<<grid, blk, 0, stream>>>(out, ws0, b1, ka, kb);
  tf2x32(0u, 42u, 0u, 3u, ka, kb);
  nca_step<1, 0><<<grid, blk, 0, stream>>>(ws0, out, b1, ka, kb);
}